// Round 5
// baseline (1553.174 us; speedup 1.0000x reference)
//
#include <hip/hip_runtime.h>

// Correlation layer v9.
// History: v4 308us (LDS, 2 barriers/chunk, sync staging); v5 FAILED (exec-
//   masked global_load_lds -> wave-uniform base shifted edge tiles); v6
//   1037us ((576,5) strangled allocator -> acc spilled, WRITE 2.5GB); v7
//   256us (reg-staged dbuf pipeline, 1 barrier/chunk, 84 VGPR); v8 354us
//   (no LDS, L1-only sharing: 9x L1 traffic, lost to v7).
// v7/v8 counters agree: VALU-busy ~41us in every variant, rest is exposed
//   latency; occupancy pinned ~25% (one 9-wave block/CU; 84 VGPR -> 128
//   bucket -> 4 waves/SIMD in v7). LDS sharing is worth +100us (v8 ablation).
// v9: buy occupancy with registers. Thread = 2 px x 9 j -> 18 acc, ~52 VGPR
//   natural -> 64-bucket -> 3 blocks (27 waves) resident/CU. Tile 8x16,
//   x2 tile 16x24 floats/channel, dbuf 12.3KB (3 blocks = 37KB LDS/CU).
//   Keeps v7's pipeline: reg-staged double buffer, ONE barrier per chunk,
//   x1 issued before stage loads, chunk-invariant pre-zeroed OOB slots,
//   XCD swizzle. Barrier drains of one block now hide behind two others.

#define B_  8
#define C_  128
#define H_  128
#define W_  192
#define HW_ (H_*W_)
#define HALO 4
#define WT  16              // tile width (px)
#define HT  8               // tile height (px)
#define CC  4               // channels per chunk
#define NCHUNK (C_/CC)      // 32
#define X2C 24              // tile row width incl halo (floats)
#define X2R 16              // tile rows incl halo
#define X2SZ (X2R*X2C)      // 384 floats per channel
#define BUFSZ (CC*X2SZ)     // 1536 floats per buffer
#define NSLOT (BUFSZ/4)     // 384 float4 staging slots
#define NTHREADS 576        // 8 x 8 x 9 = 9 waves

__global__ __launch_bounds__(NTHREADS, 7) void corr_kernel(
    const float* __restrict__ x1, const float* __restrict__ x2,
    float* __restrict__ out)
{
    __shared__ float x2s[2][BUFSZ];   // 2*1536*4 = 12288 B

    const int tx = threadIdx.x;           // 0..7 : 2-px column group
    const int ty = threadIdx.y;           // 0..7 : row within tile
    const int iz = threadIdx.z;           // 0..8 : displacement row (one wave)
    const int tid = tx + 8*ty + 64*iz;    // 0..575

    // XCD swizzle: bid&7 pins one batch image per XCD; tiles row-major.
    const int bid = blockIdx.x;
    const int b   = bid & 7;
    const int t   = bid >> 3;             // 0..191
    const int w0t = (t % 12) * WT;
    const int h0t = (t / 12) * HT;

    const float* x1b = x1 + (size_t)b * C_ * HW_;
    const float* x2b = x2 + (size_t)b * C_ * HW_;

    // ---- staging float4 slot (chunk-invariant); threads tid<384 stage ----
    const bool stager = (tid < NSLOT);
    const int e   = stager ? tid : 0;
    const int ch0 = e / 96;                    // 96 float4 per channel
    const int rem = e - 96*ch0;
    const int r0  = rem / 6;                   // 6 float4 per row
    const int cq0 = rem - 6*r0;
    const int gh0 = h0t - HALO + r0;
    const int gw0 = w0t - HALO + 4*cq0;        // 4-aligned; f4 fully in or out
    const bool inb0 = stager && ((unsigned)gh0 < (unsigned)H_)
                             && ((unsigned)gw0 < (unsigned)W_);
    const int  l0   = 4 * e;                   // linear float offset in buffer
    const float* ps0 = x2b + (inb0 ? ((long)ch0 * HW_ + (long)gh0 * W_ + gw0) : 0);
    const long  st0 = inb0 ? (long)CC * HW_ : 0;   // OOB: reload same addr

    // OOB slots: zero once in BOTH buffers; never rewritten afterwards.
    if (stager && !inb0) {
        const float4 fz = make_float4(0.f, 0.f, 0.f, 0.f);
        *(float4*)&x2s[0][l0] = fz;
        *(float4*)&x2s[1][l0] = fz;
    }

    // prologue: stage chunk 0 into buffer 0
    if (stager) {
        const float4 t0 = *(const float4*)ps0;
        if (inb0) *(float4*)&x2s[0][l0] = t0;
    }
    __syncthreads();

    const int h_out = h0t + ty;
    const int w_out = w0t + 2 * tx;
    const float* x1t = x1b + (size_t)h_out * W_ + w_out;
    const int woff = (ty + iz) * X2C + 2 * tx;   // even -> 8B aligned

    float acc[9][2];
    #pragma unroll
    for (int j = 0; j < 9; j++) { acc[j][0] = 0.f; acc[j][1] = 0.f; }

    #pragma unroll 2
    for (int k = 0; k < NCHUNK; ++k) {
        const int cb = k * CC;
        const bool more = (k + 1 < NCHUNK);

        // x1 loads FIRST (oldest vmcnt): per-cc FMA waits retire these
        // without draining the younger stage load.
        float2 a[CC];
        #pragma unroll
        for (int cc = 0; cc < CC; ++cc)
            a[cc] = *(const float2*)(x1t + (size_t)(cb + cc) * HW_);

        // stage load for chunk k+1 -> VGPRs; in flight across the compute.
        float4 t0;
        if (more && stager)
            t0 = *(const float4*)(ps0 + (long)(k + 1) * st0);

        // compute chunk k from current buffer
        const float* buf = &x2s[k & 1][0];
        #pragma unroll
        for (int cc = 0; cc < CC; ++cc) {
            const float* row = buf + cc * X2SZ + woff;
            const float2 w0 = *(const float2*)(row);
            const float2 w1 = *(const float2*)(row + 2);
            const float2 w2 = *(const float2*)(row + 4);
            const float2 w3 = *(const float2*)(row + 6);
            const float2 w4 = *(const float2*)(row + 8);
            const float rr[10] = {w0.x, w0.y, w1.x, w1.y, w2.x,
                                  w2.y, w3.x, w3.y, w4.x, w4.y};
            const float ax = a[cc].x, ay = a[cc].y;
            #pragma unroll
            for (int j = 0; j < 9; j++) {
                acc[j][0] = fmaf(ax, rr[j],     acc[j][0]);
                acc[j][1] = fmaf(ay, rr[j + 1], acc[j][1]);
            }
        }

        // write chunk k+1 into the other buffer (per-lane DS, exec-masked)
        if (more && inb0)
            *(float4*)(&x2s[(k & 1) ^ 1][0] + l0) = t0;

        __syncthreads();   // stage visible; this chunk's reads done
    }

    // epilogue: scale + write up to 9 float2 channels
    const float scale = 0.08838834764831845f;   // 1/sqrt(128)
    float* outb = out + (size_t)b * 80 * HW_ + (size_t)h_out * W_ + w_out;
    #pragma unroll
    for (int j = 0; j < 9; j++) {
        const int gi = iz * 9 + j;          // 0..80, wave-uniform
        if (gi == 40) continue;             // skip (0,0) displacement
        const int ch = gi - (gi > 40 ? 1 : 0);
        float2 v;
        v.x = acc[j][0] * scale;
        v.y = acc[j][1] * scale;
        *(float2*)(outb + (size_t)ch * HW_) = v;
    }
}

extern "C" void kernel_launch(void* const* d_in, const int* in_sizes, int n_in,
                              void* d_out, int out_size, void* d_ws, size_t ws_size,
                              hipStream_t stream) {
    const float* x1 = (const float*)d_in[0];
    const float* x2 = (const float*)d_in[1];
    float* out = (float*)d_out;

    dim3 block(8, 8, 9);                       // 576 threads = 9 waves
    dim3 grid(12 * 16 * 8, 1, 1);              // 1536 blocks, linearized
    corr_kernel<<<grid, block, 0, stream>>>(x1, x2, out);
}